// Round 1
// baseline (260.095 us; speedup 1.0000x reference)
//
#include <hip/hip_runtime.h>

// H = hidden size = 512, fixed by the problem.
#define H 512

// Output layout (flat f32, in reference return order):
//   h_out      [H]        @ 0
//   y_out      [H]        @ 512
//   jac_W_hh   [H,H,H]    @ 1024
//   jac_W_ih   [H,H,H]    @ 1024 + H^3
//   jac_b      [H,H]      @ 1024 + 2*H^3
//   dynamics   [H,H]      @ 1024 + 2*H^3 + H^2
static constexpr long long JSZ      = (long long)H * H * H;       // 134,217,728
static constexpr long long OFF_H    = 0;
static constexpr long long OFF_Y    = H;
static constexpr long long OFF_JWHH = 2 * H;                      // 1024
static constexpr long long OFF_JWIH = OFF_JWHH + JSZ;
static constexpr long long OFF_JB   = OFF_JWHH + 2 * JSZ;
static constexpr long long OFF_DYN  = OFF_JB + (long long)H * H;

// ---------------------------------------------------------------------------
// 1) Zero-fill the jacobian region (jac_W_hh + jac_W_ih + jac_b contiguous).
//    Pure float4 streaming stores — this is ~1.0748 GB and dominates runtime.
__global__ void zero_kernel(float4* __restrict__ p, long long n4) {
    long long i = (long long)blockIdx.x * blockDim.x + threadIdx.x;
    long long stride = (long long)gridDim.x * blockDim.x;
    const float4 z = make_float4(0.f, 0.f, 0.f, 0.f);
    for (; i < n4; i += stride) p[i] = z;
}

// ---------------------------------------------------------------------------
// 2) th = tanh(h_prev); s = 1 - th^2   (stored in workspace)
__global__ void prep_kernel(const float* __restrict__ h_prev, float* __restrict__ ws) {
    int j = threadIdx.x;  // 512 threads
    float th = tanhf(h_prev[j]);
    ws[j] = th;            // ws[0..511]   = th
    ws[H + j] = 1.0f - th * th;  // ws[512..1023] = 1 - th^2
}

// ---------------------------------------------------------------------------
// 3) h_out[i] = W_hh[i,:]@th + W_ih[i,:]@x + b[i] + pert[i]
//    Also stash tanh(h_out) in ws for the y matvec.
__global__ void hmatvec_kernel(const float* __restrict__ W_hh,
                               const float* __restrict__ W_ih,
                               const float* __restrict__ x,
                               const float* __restrict__ b,
                               const float* __restrict__ pert,
                               const float* __restrict__ ws_th,
                               float* __restrict__ out_h,
                               float* __restrict__ ws_th2) {
    int i = blockIdx.x;    // row, 512 blocks
    int t = threadIdx.x;   // 256 threads
    const float* wh = W_hh + (long long)i * H;
    const float* wi = W_ih + (long long)i * H;
    float acc = 0.f;
    for (int j = t; j < H; j += 256)
        acc += wh[j] * ws_th[j] + wi[j] * x[j];
    __shared__ float sm[256];
    sm[t] = acc;
    __syncthreads();
    for (int s = 128; s > 0; s >>= 1) {
        if (t < s) sm[t] += sm[t + s];
        __syncthreads();
    }
    if (t == 0) {
        float h = sm[0] + b[i] + pert[i];
        out_h[i] = h;
        ws_th2[i] = tanhf(h);
    }
}

// ---------------------------------------------------------------------------
// 4) y_out[i] = C_w[i,:]@tanh(h_out) + D_w[i,:]@x
__global__ void ymatvec_kernel(const float* __restrict__ C_w,
                               const float* __restrict__ D_w,
                               const float* __restrict__ x,
                               const float* __restrict__ ws_th2,
                               float* __restrict__ out_y) {
    int i = blockIdx.x;
    int t = threadIdx.x;
    const float* cw = C_w + (long long)i * H;
    const float* dw = D_w + (long long)i * H;
    float acc = 0.f;
    for (int j = t; j < H; j += 256)
        acc += cw[j] * ws_th2[j] + dw[j] * x[j];
    __shared__ float sm[256];
    sm[t] = acc;
    __syncthreads();
    for (int s = 128; s > 0; s >>= 1) {
        if (t < s) sm[t] += sm[t + s];
        __syncthreads();
    }
    if (t == 0) out_y[i] = sm[0];
}

// ---------------------------------------------------------------------------
// 5) dynamics[a,b] = W_hh[a,b] * s[b]   (float4 over H*H)
__global__ void dyn_kernel(const float* __restrict__ W_hh,
                           const float* __restrict__ s,
                           float* __restrict__ out_dyn) {
    int idx = blockIdx.x * blockDim.x + threadIdx.x;  // 65536 float4s
    const float4 w = ((const float4*)W_hh)[idx];
    const float4 sv = ((const float4*)s)[idx & (H / 4 - 1)];  // column block
    float4 r;
    r.x = w.x * sv.x; r.y = w.y * sv.y; r.z = w.z * sv.z; r.w = w.w * sv.w;
    ((float4*)out_dyn)[idx] = r;
}

// ---------------------------------------------------------------------------
// 6) Fill the nonzero jacobian rows:
//    jac_W_hh[i,i,:] = th;  jac_W_ih[i,i,:] = x;  jac_b[i,i] = 1
__global__ void jacfill_kernel(const float* __restrict__ ws_th,
                               const float* __restrict__ x,
                               float* __restrict__ out) {
    int i = blockIdx.x;    // 512 blocks
    int t = threadIdx.x;   // 128 threads -> one float4 each over 512 floats
    const float4 thv = ((const float4*)ws_th)[t];
    const float4 xv  = ((const float4*)x)[t];
    long long rowoff = (long long)i * ((long long)H * H + H);  // i*(H^2+H) floats
    ((float4*)(out + OFF_JWHH + rowoff))[t] = thv;
    ((float4*)(out + OFF_JWIH + rowoff))[t] = xv;
    if (t == 0) out[OFF_JB + (long long)i * (H + 1)] = 1.0f;
}

// ---------------------------------------------------------------------------
extern "C" void kernel_launch(void* const* d_in, const int* in_sizes, int n_in,
                              void* d_out, int out_size, void* d_ws, size_t ws_size,
                              hipStream_t stream) {
    const float* h_prev = (const float*)d_in[0];
    const float* x      = (const float*)d_in[1];
    const float* pert   = (const float*)d_in[2];
    const float* W_hh   = (const float*)d_in[3];
    const float* W_ih   = (const float*)d_in[4];
    const float* b      = (const float*)d_in[5];
    const float* C_w    = (const float*)d_in[6];
    const float* D_w    = (const float*)d_in[7];
    float* out = (float*)d_out;
    float* ws  = (float*)d_ws;   // [0..511]=th, [512..1023]=1-th^2, [1024..1535]=tanh(h_out)

    // Zero jac_W_hh + jac_W_ih + jac_b (contiguous region, 2*H^3 + H^2 floats).
    long long n4 = (2 * JSZ + (long long)H * H) / 4;
    zero_kernel<<<2048, 256, 0, stream>>>((float4*)(out + OFF_JWHH), n4);

    prep_kernel<<<1, H, 0, stream>>>(h_prev, ws);
    hmatvec_kernel<<<H, 256, 0, stream>>>(W_hh, W_ih, x, b, pert, ws,
                                          out + OFF_H, ws + 2 * H);
    ymatvec_kernel<<<H, 256, 0, stream>>>(C_w, D_w, x, ws + 2 * H, out + OFF_Y);
    dyn_kernel<<<H * H / 4 / 256, 256, 0, stream>>>(W_hh, ws + H, out + OFF_DYN);
    jacfill_kernel<<<H, 128, 0, stream>>>(ws, x, out);
}